// Round 5
// baseline (355.749 us; speedup 1.0000x reference)
//
#include <hip/hip_runtime.h>
#include <math.h>

#define BATCH 64
#define APB 512
#define NA 6
#define NG 5832  // 18^3

__device__ __forceinline__ float leaky(float v){ return v >= 0.f ? v : 0.01f*v; }

// ============ atom sort: deterministic counting sort by (batch, type) ============
__global__ __launch_bounds__(64) void atom_sort(const float* __restrict__ x,
                                                int* __restrict__ dst,
                                                int* __restrict__ seg_start,
                                                int* __restrict__ seg_count)
{
  int batch = blockIdx.x;
  int lane  = threadIdx.x;
  int tyc[8];
  int cnt[NA];
  #pragma unroll
  for (int t = 0; t < NA; t++) cnt[t] = 0;
  #pragma unroll
  for (int c = 0; c < 8; c++){
    int a = batch*APB + c*64 + lane;
    int ty = (int)x[(size_t)a*5 + 1];
    tyc[c] = ty;
    #pragma unroll
    for (int t = 0; t < NA; t++){
      unsigned long long m = __ballot(ty == t);
      cnt[t] += __popcll(m);
    }
  }
  int pre[NA+1];
  pre[0] = 0;
  #pragma unroll
  for (int t = 0; t < NA; t++) pre[t+1] = pre[t] + cnt[t];
  if (lane < NA){
    seg_start[batch*NA + lane] = batch*APB + pre[lane];
    seg_count[batch*NA + lane] = cnt[lane];
  }
  int run[NA];
  #pragma unroll
  for (int t = 0; t < NA; t++) run[t] = pre[t];
  unsigned long long below = (lane == 0) ? 0ull : ((~0ull) >> (64 - lane));
  #pragma unroll
  for (int c = 0; c < 8; c++){
    int a = batch*APB + c*64 + lane;
    int ty = tyc[c];
    int rank = 0;
    #pragma unroll
    for (int t = 0; t < NA; t++){
      unsigned long long m = __ballot(ty == t);
      if (ty == t) rank = run[t] + __popcll(m & below);
      run[t] += __popcll(m);
    }
    dst[a] = batch*APB + rank;
  }
}

// ============ blur phase 1: per-atom separable 1-D tables (sorted rows) ============
__global__ __launch_bounds__(256) void blur_prep(const float* __restrict__ x,
                                                 const int* __restrict__ dst,
                                                 float* __restrict__ tab)
{
  int a = blockIdx.x*256 + threadIdx.x;
  if (a >= BATCH*APB) return;
  const float* row = x + (size_t)a*5;
  float p0 = row[2], p1 = row[3], p2 = row[4];
  float e[54];
  float s0 = 0.f, s1 = 0.f, s2 = 0.f;
  #pragma unroll
  for (int i = 0; i < 18; i++){
    float g = (float)i - 8.5f;
    float d0 = p0 - g, d1 = p1 - g, d2 = p2 - g;
    float v0 = __expf(d0*d0 * (-1.f/0.72f));
    float v1 = __expf(d1*d1 * (-1.f/0.72f));
    float v2 = __expf(d2*d2 * (-1.f/0.72f));
    e[i] = v0; e[18+i] = v1; e[36+i] = v2;
    s0 += v0; s1 += v1; s2 += v2;
  }
  float inv = 1.f / (s0*s1*s2 + 1e-6f);
  float* tp = tab + (size_t)dst[a]*64;
  #pragma unroll
  for (int i = 0; i < 18; i++) tp[i] = e[i]*inv;
  tp[18] = 0.f; tp[19] = 0.f;
  #pragma unroll
  for (int i = 0; i < 18; i++) tp[20+i] = e[18+i];
  #pragma unroll
  for (int i = 0; i < 18; i++) tp[40+i] = e[36+i];
}

// ============ blur phase 2: branch-free streaming outer-product ============
__global__ __launch_bounds__(192) void blur_accum(const float* __restrict__ tab,
                                                  const int* __restrict__ seg_start,
                                                  const int* __restrict__ seg_count,
                                                  float* __restrict__ fields)
{
  int bid  = blockIdx.x;
  int seg  = bid >> 1;
  int half = bid & 1;
  int tid = threadIdx.x;
  bool act = tid < 162;
  int ix = half*9 + tid/18;
  int iy = tid % 18;

  float acc[18];
  #pragma unroll
  for (int k = 0; k < 18; k++) acc[k] = 0.f;

  int start = seg_start[seg], count = seg_count[seg];
  const float* tb = tab + (size_t)start*64;

  int j = 0;
  for (; j + 3 < count; j += 4){
    const float* t0 = tb + (size_t)(j+0)*64;
    const float* t1 = tb + (size_t)(j+1)*64;
    const float* t2 = tb + (size_t)(j+2)*64;
    const float* t3 = tb + (size_t)(j+3)*64;
    float e0 = t0[ix]*t0[20+iy];
    float e1 = t1[ix]*t1[20+iy];
    float e2 = t2[ix]*t2[20+iy];
    float e3 = t3[ix]*t3[20+iy];
    #pragma unroll
    for (int k = 0; k < 18; k++){
      float a = acc[k];
      a = fmaf(e0, t0[40+k], a);
      a = fmaf(e1, t1[40+k], a);
      a = fmaf(e2, t2[40+k], a);
      a = fmaf(e3, t3[40+k], a);
      acc[k] = a;
    }
  }
  for (; j < count; j++){
    const float* t0 = tb + (size_t)j*64;
    float e0 = t0[ix]*t0[20+iy];
    #pragma unroll
    for (int k = 0; k < 18; k++)
      acc[k] = fmaf(e0, t0[40+k], acc[k]);
  }
  if (act){
    float* fo = fields + (size_t)seg*NG + (size_t)(ix*18 + iy)*18;
    #pragma unroll
    for (int k = 0; k < 18; k++) fo[k] = acc[k];
  }
}

// ============ conv0: 6->16, 18^3 -> pool 9^3; padded/aligned LDS + fused stats ============
// in_s[ic][zl][yrow 0..19][pitch 20]: y rows 1..18 hold gy 0..17, rows 0/19 zero.
__global__ __launch_bounds__(192) void conv0_kernel(const float* __restrict__ in,
                                                    const float* __restrict__ w,
                                                    const float* __restrict__ bias,
                                                    float* __restrict__ out,
                                                    float* __restrict__ part)
{
  __shared__ float in_s[6*4*20*20];   // 9600 floats, rows 16B-aligned
  __shared__ float w_s[2592];
  __shared__ float red_s[288];
  int bid = blockIdx.x;
  int b = bid / 9, pz = bid - b*9;
  int tid = threadIdx.x;

  for (int idx = tid; idx < 9600; idx += 192){
    int xx = idx % 20; int t = idx / 20;
    int yi = t % 20;   int t2 = t / 20;
    int zl = t2 % 4;   int ic = t2 / 4;
    int gz = 2*pz - 1 + zl;
    float v = 0.f;
    if (xx < 18 && yi >= 1 && yi <= 18 && (unsigned)gz < 18u)
      v = in[(size_t)(b*6+ic)*5832 + gz*324 + (yi-1)*18 + xx];
    in_s[idx] = v;
  }
  for (int idx = tid; idx < 2592; idx += 192) w_s[idx] = w[idx];
  __syncthreads();

  float s_stat = 0.f, s2_stat = 0.f;
  int oc = tid / 9, py = tid - oc*9;   // valid when tid<144
  if (tid < 144){
    float acc[2][2][18];
    #pragma unroll
    for (int i=0;i<2;i++)
      #pragma unroll
      for (int j=0;j<2;j++)
        #pragma unroll
        for (int k=0;k<18;k++) acc[i][j][k]=0.f;

    for (int ic=0; ic<6; ic++){
      float wr[27];
      #pragma unroll
      for (int k=0;k<27;k++) wr[k] = w_s[(oc*6+ic)*27 + k];
      #pragma unroll
      for (int zl=0; zl<4; zl++){
        #pragma unroll
        for (int yl=0; yl<4; yl++){
          int yrow = 2*py + yl;        // gy+1, always in [0,19]
          const float* rp = &in_s[((ic*4+zl)*20 + yrow)*20];
          float row[18];
          *(float4*)&row[0]  = *(const float4*)(rp);
          *(float4*)&row[4]  = *(const float4*)(rp+4);
          *(float4*)&row[8]  = *(const float4*)(rp+8);
          *(float4*)&row[12] = *(const float4*)(rp+12);
          *(float2*)&row[16] = *(const float2*)(rp+16);
          #pragma unroll
          for (int czl=0; czl<2; czl++){
            if (zl-czl < 0 || zl-czl > 2) continue;
            #pragma unroll
            for (int cyl=0; cyl<2; cyl++){
              if (yl-cyl < 0 || yl-cyl > 2) continue;
              const int wb = (zl-czl)*9 + (yl-cyl)*3;
              #pragma unroll
              for (int cx=0; cx<18; cx++){
                float a = acc[czl][cyl][cx];
                #pragma unroll
                for (int dx=0; dx<3; dx++){
                  int sx = cx - 1 + dx;
                  if (sx >= 0 && sx < 18) a = fmaf(row[sx], wr[wb+dx], a);
                }
                acc[czl][cyl][cx] = a;
              }
            }
          }
        }
      }
    }
    float bb = bias[oc];
    float* op = out + (((size_t)(b*16 + oc)*9 + pz)*9 + py)*9;
    #pragma unroll
    for (int px=0; px<9; px++){
      float m = acc[0][0][2*px];
      m = fmaxf(m, acc[0][0][2*px+1]);
      m = fmaxf(m, acc[0][1][2*px]);  m = fmaxf(m, acc[0][1][2*px+1]);
      m = fmaxf(m, acc[1][0][2*px]);  m = fmaxf(m, acc[1][0][2*px+1]);
      m = fmaxf(m, acc[1][1][2*px]);  m = fmaxf(m, acc[1][1][2*px+1]);
      float v = m + bb;
      op[px] = v;
      s_stat += v; s2_stat += v*v;
    }
  }
  __syncthreads();
  if (tid < 144){ red_s[tid] = s_stat; red_s[144+tid] = s2_stat; }
  __syncthreads();
  if (tid < 16){
    float s = 0.f, s2 = 0.f;
    #pragma unroll
    for (int p = 0; p < 9; p++){ s += red_s[tid*9+p]; s2 += red_s[144+tid*9+p]; }
    part[(size_t)(tid*576 + bid)*2]     = s;
    part[(size_t)(tid*576 + bid)*2 + 1] = s2;
  }
}

// ============ conv1: 16->32, 9^3 -> pool 4^3; BN0 fused; oc-half split; fused stats ============
// in_s[ic][zl][yrow 0..9][pitch 12]: x stored at idx x+1 (1..9), y rows 1..9 = gy 0..8.
__global__ __launch_bounds__(128) void conv1_kernel(const float* __restrict__ in,
                                                    const float* __restrict__ w,
                                                    const float* __restrict__ bias,
                                                    const float* __restrict__ sc,
                                                    const float* __restrict__ sh,
                                                    float* __restrict__ out,
                                                    float* __restrict__ part)
{
  __shared__ float in_s[16*4*10*12];   // 7680 floats
  int bid = blockIdx.x;                // (b, pz, oh)
  int b = bid >> 3, pz = (bid >> 1) & 3, oh = bid & 1;
  int tid = threadIdx.x;

  for (int idx = tid; idx < 7680; idx += 128){
    int xi = idx % 12; int t = idx / 12;
    int yi = t % 10;   int t2 = t / 10;
    int zl = t2 % 4;   int ic = t2 / 4;
    int gz = 2*pz - 1 + zl;
    float v = 0.f;
    if (xi >= 1 && xi <= 9 && yi >= 1 && yi <= 9 && (unsigned)gz < 9u){
      float raw = in[(size_t)(b*16+ic)*729 + gz*81 + (yi-1)*9 + (xi-1)];
      v = leaky(fmaf(raw, sc[ic], sh[ic]));
    }
    in_s[idx] = v;
  }
  __syncthreads();

  int ocl = tid >> 3, py = (tid >> 1) & 3, xh = tid & 1;
  int oc = oh*16 + ocl;
  float acc[2][2][4];
  #pragma unroll
  for (int i=0;i<2;i++)
    #pragma unroll
    for (int j=0;j<2;j++)
      #pragma unroll
      for (int k=0;k<4;k++) acc[i][j][k]=0.f;

  const float* wp_base = w + (size_t)oc*16*27;
  for (int ic=0; ic<16; ic++){
    float wr[27];
    #pragma unroll
    for (int k=0;k<27;k++) wr[k] = wp_base[ic*27 + k];
    #pragma unroll
    for (int zl=0; zl<4; zl++){
      #pragma unroll
      for (int yl=0; yl<4; yl++){
        int yrow = 2*py + yl;          // gy+1 in [0,9]
        const float* rp = &in_s[((ic*4+zl)*10 + yrow)*12 + 4*xh];
        float row[6];
        *(float4*)&row[0] = *(const float4*)(rp);
        *(float2*)&row[4] = *(const float2*)(rp+4);
        #pragma unroll
        for (int czl=0;czl<2;czl++){
          if (zl-czl<0||zl-czl>2) continue;
          #pragma unroll
          for (int cyl=0;cyl<2;cyl++){
            if (yl-cyl<0||yl-cyl>2) continue;
            const int wb = (zl-czl)*9+(yl-cyl)*3;
            #pragma unroll
            for (int cx=0;cx<4;cx++){
              float a = acc[czl][cyl][cx];
              #pragma unroll
              for (int dx=0;dx<3;dx++) a = fmaf(row[cx+dx], wr[wb+dx], a);
              acc[czl][cyl][cx]=a;
            }
          }
        }
      }
    }
  }
  float bb = bias[oc];
  float s_stat = 0.f, s2_stat = 0.f;
  float* op = out + (((size_t)(b*32+oc)*4 + pz)*4 + py)*4 + xh*2;
  #pragma unroll
  for (int p=0;p<2;p++){
    float m = acc[0][0][2*p];  m=fmaxf(m,acc[0][0][2*p+1]);
    m=fmaxf(m,acc[0][1][2*p]); m=fmaxf(m,acc[0][1][2*p+1]);
    m=fmaxf(m,acc[1][0][2*p]); m=fmaxf(m,acc[1][0][2*p+1]);
    m=fmaxf(m,acc[1][1][2*p]); m=fmaxf(m,acc[1][1][2*p+1]);
    float v = m + bb;
    op[p] = v;
    s_stat += v; s2_stat += v*v;
  }
  // reduce over the 8 threads (py,xh) sharing this oc (8 consecutive lanes)
  #pragma unroll
  for (int d = 4; d > 0; d >>= 1){
    s_stat  += __shfl_down(s_stat,  d, 8);
    s2_stat += __shfl_down(s2_stat, d, 8);
  }
  if ((tid & 7) == 0){
    part[(size_t)(oc*256 + b*4 + pz)*2]     = s_stat;
    part[(size_t)(oc*256 + b*4 + pz)*2 + 1] = s2_stat;
  }
}

// ============ conv2: 32->64, 4^3 -> pool 2^3; BN1 fused; oc-quarter split; transposed out ============
// in_s[ic][zl][yrow 0..5][pitch 8]: x at idx x+1 (1..4), y rows 1..4 = gy 0..3.
__global__ __launch_bounds__(64) void conv2_kernel(const float* __restrict__ in,
                                                   const float* __restrict__ w,
                                                   const float* __restrict__ bias,
                                                   const float* __restrict__ sc,
                                                   const float* __restrict__ sh,
                                                   float* __restrict__ out)  // [64ch*8sp][64b]
{
  __shared__ float in_s[32*4*6*8];   // 6144 floats
  int bid = blockIdx.x;              // (b, pz, oq)
  int b = bid >> 3, pz = (bid >> 2) & 1, oq = bid & 3;
  int tid = threadIdx.x;

  for (int idx = tid; idx < 6144; idx += 64){
    int xi = idx % 8; int t = idx / 8;
    int yi = t % 6;   int t2 = t / 6;
    int zl = t2 % 4;  int ic = t2 / 4;
    int gz = 2*pz - 1 + zl;
    float v = 0.f;
    if (xi >= 1 && xi <= 4 && yi >= 1 && yi <= 4 && (unsigned)gz < 4u){
      float raw = in[(size_t)(b*32+ic)*64 + gz*16 + (yi-1)*4 + (xi-1)];
      v = leaky(fmaf(raw, sc[ic], sh[ic]));
    }
    in_s[idx] = v;
  }
  __syncthreads();

  int oc = oq*16 + (tid >> 2), py = (tid >> 1) & 1, px = tid & 1;
  float acc[2][2][2];
  #pragma unroll
  for (int i=0;i<2;i++)
    #pragma unroll
    for (int j=0;j<2;j++)
      #pragma unroll
      for (int k=0;k<2;k++) acc[i][j][k]=0.f;

  const float* wp_base = w + (size_t)oc*32*27;
  for (int ic = 0; ic < 32; ic++){
    float wr[27];
    #pragma unroll
    for (int k=0;k<27;k++) wr[k] = wp_base[ic*27 + k];
    #pragma unroll
    for (int zl=0; zl<4; zl++){
      #pragma unroll
      for (int yl=0; yl<4; yl++){
        int yrow = 2*py + yl;           // gy+1 in [0,5]
        const float* rp = &in_s[((ic*4+zl)*6 + yrow)*8 + 2*px];
        float row[4];
        *(float2*)&row[0] = *(const float2*)(rp);
        *(float2*)&row[2] = *(const float2*)(rp+2);
        #pragma unroll
        for (int czl=0;czl<2;czl++){
          if (zl-czl<0||zl-czl>2) continue;
          #pragma unroll
          for (int cyl=0;cyl<2;cyl++){
            if (yl-cyl<0||yl-cyl>2) continue;
            const int wb=(zl-czl)*9+(yl-cyl)*3;
            #pragma unroll
            for (int cx=0;cx<2;cx++){
              float a = acc[czl][cyl][cx];
              #pragma unroll
              for (int dx=0;dx<3;dx++) a=fmaf(row[cx+dx],wr[wb+dx],a);
              acc[czl][cyl][cx]=a;
            }
          }
        }
      }
    }
  }
  float bb = bias[oc];
  float m = acc[0][0][0];
  m=fmaxf(m,acc[0][0][1]); m=fmaxf(m,acc[0][1][0]); m=fmaxf(m,acc[0][1][1]);
  m=fmaxf(m,acc[1][0][0]); m=fmaxf(m,acc[1][0][1]); m=fmaxf(m,acc[1][1][0]); m=fmaxf(m,acc[1][1][1]);
  out[(size_t)(oc*8 + pz*4 + py*2 + px)*64 + b] = m + bb;
}

// ---------------- stats finalize: per-channel partials -> scale/shift ----------------
template<int C, int N>
__global__ __launch_bounds__(256) void stats_final(const float* __restrict__ part,
                                                   float* __restrict__ scale,
                                                   float* __restrict__ shift,
                                                   const float* __restrict__ g,
                                                   const float* __restrict__ bb,
                                                   float n)
{
  int c = blockIdx.x;
  float s = 0.f, s2 = 0.f;
  for (int i = threadIdx.x; i < N; i += 256){
    s  += part[(size_t)(c*N + i)*2];
    s2 += part[(size_t)(c*N + i)*2 + 1];
  }
  #pragma unroll
  for (int d = 32; d > 0; d >>= 1){ s += __shfl_down(s, d); s2 += __shfl_down(s2, d); }
  __shared__ float rs[4], rq[4];
  int lane = threadIdx.x & 63, wid = threadIdx.x >> 6;
  if (lane == 0){ rs[wid] = s; rq[wid] = s2; }
  __syncthreads();
  if (threadIdx.x == 0){
    float ts = rs[0]+rs[1]+rs[2]+rs[3];
    float tq = rq[0]+rq[1]+rq[2]+rq[3];
    float m = ts / n;
    float var = tq / n - m*m;
    float is = rsqrtf(var + 1e-5f);
    float scv = is * g[c];
    scale[c] = scv;
    shift[c] = bb[c] - m * scv;
  }
}

// ---------------- BN2 stats on transposed p2t: one wave per channel ----------------
__global__ __launch_bounds__(256) void bn2t_kernel(const float* __restrict__ p2t,
                                                   const float* __restrict__ g,
                                                   const float* __restrict__ bb,
                                                   float* __restrict__ scale,
                                                   float* __restrict__ shift)
{
  int gt = blockIdx.x*256 + threadIdx.x;
  int c = gt >> 6, lane = gt & 63;
  if (c >= 64) return;
  const float* p = p2t + (size_t)c*512;
  float s = 0.f, s2 = 0.f;
  #pragma unroll
  for (int i = 0; i < 8; i++){ float v = p[i*64 + lane]; s += v; s2 += v*v; }
  #pragma unroll
  for (int d = 32; d > 0; d >>= 1){ s += __shfl_down(s, d); s2 += __shfl_down(s2, d); }
  if (lane == 0){
    float m = s * (1.f/512.f);
    float var = s2 * (1.f/512.f) - m*m;
    float scv = rsqrtf(var + 1e-5f) * g[c];
    scale[c] = scv;
    shift[c] = bb[c] - m*scv;
  }
}

// ---------------- fc0 (512->512) + BN2-on-load + batch-BN3 + leaky, wave/feature ----------------
__global__ __launch_bounds__(256) void fc0bn_kernel(const float* __restrict__ p2t,
                                                    const float* __restrict__ W,
                                                    const float* __restrict__ bias,
                                                    const float* __restrict__ sc,
                                                    const float* __restrict__ sh,
                                                    const float* __restrict__ g,
                                                    const float* __restrict__ bb,
                                                    float* __restrict__ y0t)
{
  int gt = blockIdx.x*256 + threadIdx.x;
  int f = gt >> 6, r = gt & 63;
  const float* wr = W + (size_t)f*512;
  float a = 0.f;
  for (int c = 0; c < 64; c++){
    float s = sc[c], h = sh[c];
    #pragma unroll
    for (int jj = 0; jj < 8; jj++){
      int i = c*8 + jj;
      float xv = leaky(fmaf(p2t[(size_t)i*64 + r], s, h));
      a = fmaf(xv, wr[i], a);
    }
  }
  a += bias[f];
  float s1 = a, s2 = a*a;
  #pragma unroll
  for (int d = 32; d > 0; d >>= 1){ s1 += __shfl_down(s1, d); s2 += __shfl_down(s2, d); }
  s1 = __shfl(s1, 0); s2 = __shfl(s2, 0);
  float m = s1 * (1.f/64.f);
  float var = s2 * (1.f/64.f) - m*m;
  float is = rsqrtf(var + 1e-5f);
  y0t[(size_t)f*64 + r] = leaky((a - m) * is * g[f] + bb[f]);
}

// ---------------- fc1 (512->256) + batch-BN4 + leaky, wave/feature ----------------
__global__ __launch_bounds__(256) void fc1bn_kernel(const float* __restrict__ y0t,
                                                    const float* __restrict__ W,
                                                    const float* __restrict__ bias,
                                                    const float* __restrict__ g,
                                                    const float* __restrict__ bb,
                                                    float* __restrict__ y1t)
{
  int gt = blockIdx.x*256 + threadIdx.x;
  int f = gt >> 6, r = gt & 63;
  const float* wr = W + (size_t)f*512;
  float a = 0.f;
  #pragma unroll 4
  for (int i = 0; i < 512; i++)
    a = fmaf(y0t[(size_t)i*64 + r], wr[i], a);
  a += bias[f];
  float s1 = a, s2 = a*a;
  #pragma unroll
  for (int d = 32; d > 0; d >>= 1){ s1 += __shfl_down(s1, d); s2 += __shfl_down(s2, d); }
  s1 = __shfl(s1, 0); s2 = __shfl(s2, 0);
  float m = s1 * (1.f/64.f);
  float var = s2 * (1.f/64.f) - m*m;
  float is = rsqrtf(var + 1e-5f);
  y1t[(size_t)f*64 + r] = leaky((a - m) * is * g[f] + bb[f]);
}

// ---------------- fc2 (256->100) + leaky, wave/feature ----------------
__global__ __launch_bounds__(256) void fc2_kernel(const float* __restrict__ y1t,
                                                  const float* __restrict__ W,
                                                  const float* __restrict__ bias,
                                                  float* __restrict__ y2t)
{
  int gt = blockIdx.x*256 + threadIdx.x;
  int f = gt >> 6, r = gt & 63;
  if (f >= 100) return;
  const float* wr = W + (size_t)f*256;
  float a = 0.f;
  #pragma unroll 4
  for (int i = 0; i < 256; i++)
    a = fmaf(y1t[(size_t)i*64 + r], wr[i], a);
  y2t[(size_t)f*64 + r] = leaky(a + bias[f]);
}

// ---------------- head (100->20), wave/output ----------------
__global__ __launch_bounds__(256) void head_kernel(const float* __restrict__ y2t,
                                                   const float* __restrict__ W,
                                                   const float* __restrict__ bias,
                                                   float* __restrict__ out)
{
  int gt = blockIdx.x*256 + threadIdx.x;
  int oo = gt >> 6, r = gt & 63;
  if (oo >= 20) return;
  const float* wr = W + (size_t)oo*100;
  float a = 0.f;
  #pragma unroll 4
  for (int i = 0; i < 100; i++)
    a = fmaf(y2t[(size_t)i*64 + r], wr[i], a);
  out[(size_t)r*20 + oo] = a + bias[oo];
}

extern "C" void kernel_launch(void* const* d_in, const int* in_sizes, int n_in,
                              void* d_out, int out_size, void* d_ws, size_t ws_size,
                              hipStream_t stream)
{
  const float* x   = (const float*)d_in[0];
  const float* cw0 = (const float*)d_in[2];  const float* cb0 = (const float*)d_in[3];
  const float* g0  = (const float*)d_in[4];  const float* bb0 = (const float*)d_in[5];
  const float* cw1 = (const float*)d_in[6];  const float* cb1 = (const float*)d_in[7];
  const float* g1  = (const float*)d_in[8];  const float* bb1 = (const float*)d_in[9];
  const float* cw2 = (const float*)d_in[10]; const float* cb2 = (const float*)d_in[11];
  const float* g2  = (const float*)d_in[12]; const float* bb2 = (const float*)d_in[13];
  const float* mw0 = (const float*)d_in[14]; const float* mb0 = (const float*)d_in[15];
  const float* g3  = (const float*)d_in[16]; const float* bb3 = (const float*)d_in[17];
  const float* mw1 = (const float*)d_in[18]; const float* mb1 = (const float*)d_in[19];
  const float* g4  = (const float*)d_in[20]; const float* bb4 = (const float*)d_in[21];
  const float* mw2 = (const float*)d_in[22]; const float* mb2 = (const float*)d_in[23];
  const float* hw  = (const float*)d_in[24]; const float* hb  = (const float*)d_in[25];

  float* ws     = (float*)d_ws;
  float* fields = ws;                    // 2239488
  float* p0     = fields + 2239488;      // 746496
  float* p1     = p0 + 746496;           // 131072
  float* p2t    = p1 + 131072;           // 32768   [512][64]
  float* y0t    = p2t + 32768;           // 32768   [512][64]
  float* y1t    = y0t + 32768;           // 16384   [256][64]
  float* y2t    = y1t + 16384;           // 6400    [100][64]
  float* part   = y2t + 6400;            // max 16*576*2 = 18432
  float* sc0    = part + 18432;          // 16
  float* sh0    = sc0 + 16;
  float* sc1    = sh0 + 16;              // 32
  float* sh1    = sc1 + 32;
  float* sc2    = sh1 + 32;              // 64
  float* sh2    = sc2 + 64;
  float* tab    = sh2 + 64;              // 32768*64 = 2097152
  int*   dst    = (int*)(tab + 2097152); // 32768
  int*   sstart = dst + 32768;           // 384
  int*   scount = sstart + 384;          // 384
  float* outp   = (float*)d_out;

  atom_sort<<<64, 64, 0, stream>>>(x, dst, sstart, scount);
  blur_prep<<<128, 256, 0, stream>>>(x, dst, tab);
  blur_accum<<<768, 192, 0, stream>>>(tab, sstart, scount, fields);

  conv0_kernel<<<576, 192, 0, stream>>>(fields, cw0, cb0, p0, part);
  stats_final<16,576><<<16, 256, 0, stream>>>(part, sc0, sh0, g0, bb0, 64.f*729.f);

  conv1_kernel<<<512, 128, 0, stream>>>(p0, cw1, cb1, sc0, sh0, p1, part);
  stats_final<32,256><<<32, 256, 0, stream>>>(part, sc1, sh1, g1, bb1, 64.f*64.f);

  conv2_kernel<<<512, 64, 0, stream>>>(p1, cw2, cb2, sc1, sh1, p2t);
  bn2t_kernel<<<16, 256, 0, stream>>>(p2t, g2, bb2, sc2, sh2);

  fc0bn_kernel<<<128, 256, 0, stream>>>(p2t, mw0, mb0, sc2, sh2, g3, bb3, y0t);
  fc1bn_kernel<<<64, 256, 0, stream>>>(y0t, mw1, mb1, g4, bb4, y1t);
  fc2_kernel<<<25, 256, 0, stream>>>(y1t, mw2, mb2, y2t);
  head_kernel<<<5, 256, 0, stream>>>(y2t, hw, hb, outp);
}